// Round 9
// baseline (185.386 us; speedup 1.0000x reference)
//
#include <hip/hip_runtime.h>
#include <math.h>

#define T_ 16
#define B_ 16
#define C_ 8
#define H_ 128
#define W_ 128
#define HW_ (H_*W_)
#define CHW_ (C_*HW_)
#define TC 4                          // t-chunk length (4 chunks)
#define NSL 16                        // 16 slices of 8 rows

__device__ __forceinline__ float wave_sum(float v){
    #pragma unroll
    for (int o=32;o>0;o>>=1) v += __shfl_down(v,o,64);
    return v;
}
__device__ __forceinline__ float wave_max(float v){
    #pragma unroll
    for (int o=32;o>0;o>>=1) v = fmaxf(v,__shfl_down(v,o,64));
    return v;
}

// ---------------- K1a: channel-contiguous, t-chunked stats + y-field ----------------
__global__ __launch_bounds__(512, 4) void stats_kernel(
    const float* __restrict__ events, float* __restrict__ partials,
    float* __restrict__ yfield)
{
    int bid   = blockIdx.x;            // 1024 blocks
    int chunk = bid & 3;
    int s     = (bid >> 2) & 15;
    int b     = bid >> 6;
    int t0    = chunk * TC;
    int gh0   = s * 8;
    int tid   = threadIdx.x;           // 0..511
    int c     = tid >> 6;              // wave id == channel
    int lane  = tid & 63;

    __shared__ float xs[C_][1024];     // 8 x 4KB = 32 KB

    int lrow  = lane >> 3;             // 0..7
    int lcol0 = (lane & 7) * 16;       // element cols lcol0..lcol0+15
    int gh    = gh0 + lrow;
    float cnth = (gh==0 || gh==H_-1) ? 2.f : 3.f;
    float w0  = (lcol0==0)        ? 2.f : 3.f;
    float w15 = (lcol0+15==W_-1)  ? 2.f : 3.f;

    const float* base0 = events + (size_t)(t0*B_+b)*CHW_ + c*HW_ + gh*W_ + lcol0;
    const size_t tstep = (size_t)B_ * CHW_;

    float px[16];
    if (t0 > 0){
        const float* pp = base0 - tstep;
        #pragma unroll
        for (int e=0;e<16;e+=4){
            float4 v = *reinterpret_cast<const float4*>(pp + e);
            px[e]=v.x; px[e+1]=v.y; px[e+2]=v.z; px[e+3]=v.w;
        }
    } else {
        #pragma unroll
        for (int e=0;e<16;e++) px[e]=0.f;
    }

    #pragma unroll 1
    for (int tt=0; tt<TC; ++tt){
        int t = t0 + tt;
        const float* src = base0 + (size_t)tt*tstep;

        float cx[16];
        #pragma unroll
        for (int e=0;e<16;e+=4){
            float4 v = *reinterpret_cast<const float4*>(src + e);
            cx[e]=v.x; cx[e+1]=v.y; cx[e+2]=v.z; cx[e+3]=v.w;
        }

        float ssum=0.f, smax=-INFINITY, q=0.f, dsu=0.f;
        #pragma unroll
        for (int e=0;e<16;e++){
            float x = cx[e];
            ssum += x;
            smax = fmaxf(smax, x);
            float w = (e==0) ? w0 : ((e==15) ? w15 : 3.f);
            q = fmaf(w*x, x, q);
            dsu += fabsf(x - px[e]);
            px[e] = x;
        }

        #pragma unroll
        for (int e=0;e<16;e+=4){
            float4 v; v.x=cx[e]; v.y=cx[e+1]; v.z=cx[e+2]; v.w=cx[e+3];
            *reinterpret_cast<float4*>(&xs[c][lane*16 + e]) = v;
        }
        __syncthreads();

        {
            int p0 = tid * 2;
            float y0=0.f, y1=0.f;
            #pragma unroll
            for (int cc=0; cc<C_; cc++){
                y0 += xs[cc][p0];
                y1 += xs[cc][p0+1];
            }
            float2 yy; yy.x=y0; yy.y=y1;
            *reinterpret_cast<float2*>(yfield + (size_t)(t*B_+b)*HW_ + gh0*W_ + p0) = yy;
        }

        float rs = wave_sum(ssum);
        float rm = wave_max(smax);
        float rd = wave_sum(dsu);
        float rq = wave_sum(cnth * q);
        if (lane == 0){
            float4 o; o.x=rs; o.y=rm; o.z=rd; o.w=rq;
            *reinterpret_cast<float4*>(
                partials + (((size_t)(t*B_+b)*NSL + s)*C_ + c)*4) = o;
        }
        __syncthreads();
    }
}

// ---------------- K1b: m1 = sum(s1^2) from the y-field ----------------
__global__ __launch_bounds__(256) void m1_kernel(
    const float* __restrict__ yfield, float* __restrict__ m1p)
{
    int bid = blockIdx.x;            // tb*8 + s
    int s   = bid & 7;
    int tb  = bid >> 3;
    int h0  = s*16;
    int tid = threadIdx.x;
    __shared__ float yb[18][W_];

    const float* yf = yfield + (size_t)tb*HW_;
    for (int i = tid; i < 18*32; i += 256){
        int rr = i >> 5, cc = (i & 31) * 4;
        int gh = h0 - 1 + rr;
        float4 v; v.x=0.f; v.y=0.f; v.z=0.f; v.w=0.f;
        if (gh >= 0 && gh < H_) v = *reinterpret_cast<const float4*>(yf + gh*W_ + cc);
        *reinterpret_cast<float4*>(&yb[rr][cc]) = v;
    }
    __syncthreads();

    float m1 = 0.f;
    {
        int w  = tid & 127;
        int rg = tid >> 7;
        bool hasL = (w>0), hasR = (w<W_-1);
        int base = rg*8;
        const float* row;
        row = yb[base];   float a0 = row[w] + (hasL?row[w-1]:0.f) + (hasR?row[w+1]:0.f);
        row = yb[base+1]; float a1 = row[w] + (hasL?row[w-1]:0.f) + (hasR?row[w+1]:0.f);
        #pragma unroll
        for (int i=0;i<8;i++){
            row = yb[base+2+i];
            float a2 = row[w] + (hasL?row[w-1]:0.f) + (hasR?row[w+1]:0.f);
            float s1 = a0 + a1 + a2;
            m1 = fmaf(s1, s1, m1);
            a0 = a1; a1 = a2;
        }
    }
    m1 = wave_sum(m1);
    __shared__ float red2[4];
    int lane = tid & 63, wv = tid >> 6;
    if (lane==0) red2[wv] = m1;
    __syncthreads();
    if (tid==0) m1p[bid] = (red2[0]+red2[1])+(red2[2]+red2[3]);
}

// ---------------- K2: combine ----------------
__global__ __launch_bounds__(64) void combine_kernel(
    const float* __restrict__ partials,
    const float* __restrict__ m1p,
    const float* __restrict__ att_w1,
    const float* __restrict__ att_w2,
    const float* __restrict__ dwp, const float* __restrict__ twp,
    const float* __restrict__ mwp,
    float* __restrict__ beta_out, float* __restrict__ thr_out,
    float* __restrict__ zeropad)
{
    int tb = blockIdx.x;
    int t  = tb / B_;
    int i  = threadIdx.x;
    if (tb == 0 && i < 16) zeropad[i] = 0.f;
    __shared__ float v[19];
    const float* p = partials + (size_t)tb*NSL*C_*4;
    if (i < 8){
        float acc = 0.f;
        #pragma unroll
        for (int s=0;s<NSL;s++) acc += p[(s*C_ + i)*4 + 0];
        v[i] = acc;
    } else if (i < 16){
        int c = i - 8;
        float acc = -INFINITY;
        #pragma unroll
        for (int s=0;s<NSL;s++) acc = fmaxf(acc, p[(s*C_ + c)*4 + 1]);
        v[i] = acc;
    } else if (i == 16){
        float acc = 0.f;
        for (int k=0;k<NSL*C_;k++) acc += p[k*4 + 2];
        v[16] = acc;
    } else if (i == 17){
        const float* mp = m1p + (size_t)tb*8;
        float acc = 0.f;
        #pragma unroll
        for (int k=0;k<8;k++) acc += mp[k];
        v[17] = acc;
    } else if (i == 18){
        float acc = 0.f;
        for (int k=0;k<NSL*C_;k++) acc += p[k*4 + 3];
        v[18] = acc;
    }
    __syncthreads();
    if (i == 0){
        float h1 = 0.f;
        for (int c=0;c<C_;c++) h1 += v[8+c] * att_w1[c];
        for (int c=0;c<C_;c++) h1 += (v[c]/(float)HW_) * att_w1[C_+c];
        h1 = fmaxf(h1, 0.f);
        float total = 0.f;
        for (int c=0;c<C_;c++) total += v[c];
        float density  = total / (float)CHW_;
        float temporal = (t==0) ? 0.f : v[16] / (float)CHW_;
        float motion   = (v[18] - v[17]/72.f) / 71.f / (float)HW_;
        float z = dwp[0]*density + twp[0]*temporal + mwp[0]*motion;
        float adj = 2.f / (1.f + expf(-z));
        thr_out[tb] = 1.f + adj;
        for (int c=0;c<C_;c++){
            float sg = 1.f / (1.f + expf(-(h1 * att_w2[c])));
            beta_out[tb*C_ + c] = 0.5f + 0.45f*sg;
        }
    }
}

// ---------------- K3: LIF (R8 version, NT stores) ----------------
__device__ __forceinline__ void gload16(const float* src, float* lds_dst){
    __builtin_amdgcn_global_load_lds(
        (const __attribute__((address_space(1))) unsigned int*)src,
        (__attribute__((address_space(3))) unsigned int*)lds_dst, 16, 0, 0);
}

__device__ __forceinline__ float fast_atan(float x){
    float ax = fabsf(x);
    bool inv = ax > 1.f;
    float z  = inv ? __builtin_amdgcn_rcpf(ax) : ax;
    float z2 = z*z;
    float p = -0.0117212f;
    p = fmaf(p, z2,  0.05265332f);
    p = fmaf(p, z2, -0.11643287f);
    p = fmaf(p, z2,  0.19354346f);
    p = fmaf(p, z2, -0.33262347f);
    p = fmaf(p, z2,  0.99997726f);
    p = p * z;
    float r = inv ? (1.57079632679f - p) : p;
    return copysignf(r, x);
}

#define SROWS 10

__global__ __launch_bounds__(256, 8) void lif_kernel(
    const float* __restrict__ events,
    const float* __restrict__ conv_w,
    const float* __restrict__ beta,
    const float* __restrict__ thr,
    const float* __restrict__ zeropad,
    float* __restrict__ out)
{
    int bid  = blockIdx.x;
    int hblk = bid & 15;
    int bc   = bid >> 4;
    int b = bc >> 3, c = bc & 7;
    int h0 = hblk * 8;
    int tid = threadIdx.x;
    int wv  = tid >> 6;

    float wk[9];
    #pragma unroll
    for (int k=0;k<9;k++) wk[k] = conv_w[c*9 + k];

    __shared__ float lds[2][SROWS*W_];

    int idxA = tid,        rowA = idxA >> 5, colA = (idxA & 31) * 4;
    int idxB = 256 + tid,  rowB = idxB >> 5, colB = (idxB & 31) * 4;
    int ghA = h0 - 1 + rowA;
    int ghB = h0 - 1 + rowB;
    bool okA = (ghA >= 0) && (ghA < H_);
    bool okB = (ghB >= 0) && (ghB < H_);
    const float* baseFrame = events + ((size_t)(b * C_) + c) * HW_;
    const float* srcA0 = okA ? (baseFrame + ghA*W_ + colA) : zeropad;
    const float* srcB0 = okB ? (baseFrame + ghB*W_ + colB) : zeropad;
    const size_t tstep = (size_t)B_ * CHW_;
    size_t stepA = okA ? tstep : 0;
    size_t stepB = okB ? tstep : 0;

    int w  = tid & 127;
    int rg = tid >> 7;
    int rbase = rg * 4;
    int wl = (w > 0)    ? w-1 : 0;
    int wr = (w < W_-1) ? w+1 : W_-1;
    bool hasL = (w > 0), hasR = (w < W_-1);

    float v[4];
    #pragma unroll
    for (int i=0;i<4;i++) v[i] = 0.f;

    gload16(srcA0, &lds[0][wv*256]);
    if (wv == 0) gload16(srcB0, &lds[0][1024]);

    const float* bp = beta + (b*C_ + c);
    const float* tp = thr + b;
    float bv = bp[0];
    float th = tp[0];

    for (int t = 0; t < T_; ++t){
        int cur = t & 1, nxt = cur ^ 1;
        __syncthreads();

        if (t + 1 < T_){
            gload16(srcA0 + (size_t)(t+1)*stepA, &lds[nxt][wv*256]);
            if (wv == 0) gload16(srcB0 + (size_t)(t+1)*stepB, &lds[nxt][1024]);
        }
        float bvn = (t+1 < T_) ? bp[(size_t)(t+1)*B_*C_] : 0.f;
        float thn = (t+1 < T_) ? tp[(size_t)(t+1)*B_]    : 0.f;

        const float* L = &lds[cur][0];
        float omb = 1.f - bv;
        float* op = out + ((size_t)(t*B_+b)*C_ + c)*HW_ + h0*W_;

        const float* row0 = L + rbase*W_;
        const float* row1 = row0 + W_;
        float la = hasL ? row0[wl] : 0.f;  float ma = row0[w];  float ra = hasR ? row0[wr] : 0.f;
        float lb = hasL ? row1[wl] : 0.f;  float mb = row1[w];  float rb = hasR ? row1[wr] : 0.f;

        #pragma unroll
        for (int i=0;i<4;i++){
            const float* rowc = L + (rbase+2+i)*W_;
            float lc = hasL ? rowc[wl] : 0.f;
            float mc = rowc[w];
            float rc = hasR ? rowc[wr] : 0.f;
            float wi = wk[0]*la + wk[1]*ma + wk[2]*ra
                     + wk[3]*lb + wk[4]*mb + wk[5]*rb
                     + wk[6]*lc + wk[7]*mc + wk[8]*rc;
            float vv = fmaf(bv, v[i], omb*wi);
            float sp = fast_atan(2.f*(vv - th))*0.5f + 0.5f;
            __builtin_nontemporal_store(mb * sp, &op[(rbase+i)*W_ + w]);
            v[i] = (1.f - sp) * vv;
            la=lb; ma=mb; ra=rb; lb=lc; mb=mc; rb=rc;
        }
        __syncthreads();

        bv = bvn; th = thn;
    }
}

extern "C" void kernel_launch(void* const* d_in, const int* in_sizes, int n_in,
                              void* d_out, int out_size, void* d_ws, size_t ws_size,
                              hipStream_t stream)
{
    const float* events = (const float*)d_in[0];
    const float* conv_w = (const float*)d_in[1];
    const float* att_w1 = (const float*)d_in[2];
    const float* att_w2 = (const float*)d_in[3];
    const float* dwp    = (const float*)d_in[4];
    const float* twp    = (const float*)d_in[5];
    const float* mwp    = (const float*)d_in[6];
    float* out = (float*)d_out;

    float* ws       = (float*)d_ws;
    float* partials = ws;
    float* m1p      = partials + (size_t)T_*B_*NSL*C_*4;
    float* beta     = m1p + (size_t)T_*B_*8;
    float* thr      = beta + (size_t)T_*B_*C_;
    float* zeropad  = thr + T_*B_;
    float* yfield   = zeropad + 16;

    // === MEASUREMENT ROUND: stats launched 4x (idempotent) ===
    // timed_total = old_total + 3 * stats_timed  -> isolates stats' duration
    // in the timed (no-fill, L3-warm) environment. Profile top-5 will show
    // stats #2-4 running L3-warm even in the profiled environment.
    stats_kernel  <<<B_*NSL*4,  512, 0, stream>>>(events, partials, yfield);
    stats_kernel  <<<B_*NSL*4,  512, 0, stream>>>(events, partials, yfield);
    stats_kernel  <<<B_*NSL*4,  512, 0, stream>>>(events, partials, yfield);
    stats_kernel  <<<B_*NSL*4,  512, 0, stream>>>(events, partials, yfield);
    m1_kernel     <<<T_*B_*8,   256, 0, stream>>>(yfield, m1p);
    combine_kernel<<<T_*B_,     64,  0, stream>>>(partials, m1p, att_w1, att_w2,
                                                  dwp, twp, mwp, beta, thr, zeropad);
    lif_kernel    <<<B_*C_*16,  256, 0, stream>>>(events, conv_w, beta, thr, zeropad, out);
}

// Round 11
// 98.316 us; speedup vs baseline: 1.8856x; 1.8856x over previous
//
#include <hip/hip_runtime.h>
#include <math.h>

#define T_ 16
#define B_ 16
#define C_ 8
#define H_ 128
#define W_ 128
#define HW_ (H_*W_)
#define CHW_ (C_*HW_)
#define TC 4                          // stats t-chunk length
#define NSL 16                        // 16 slices of 8 rows

typedef float __attribute__((ext_vector_type(4))) f32x4;

__device__ __forceinline__ float wave_sum(float v){
    #pragma unroll
    for (int o=32;o>0;o>>=1) v += __shfl_down(v,o,64);
    return v;
}
__device__ __forceinline__ float wave_max(float v){
    #pragma unroll
    for (int o=32;o>0;o>>=1) v = fmaxf(v,__shfl_down(v,o,64));
    return v;
}

// ---------------- K1a: channel-contiguous, t-chunked stats + y-field (R8, at BW roofline) ----------------
__global__ __launch_bounds__(512, 4) void stats_kernel(
    const float* __restrict__ events, float* __restrict__ partials,
    float* __restrict__ yfield)
{
    int bid   = blockIdx.x;            // 1024 blocks
    int chunk = bid & 3;
    int s     = (bid >> 2) & 15;
    int b     = bid >> 6;
    int t0    = chunk * TC;
    int gh0   = s * 8;
    int tid   = threadIdx.x;           // 0..511
    int c     = tid >> 6;              // wave id == channel
    int lane  = tid & 63;

    __shared__ float xs[C_][1024];     // 32 KB

    int lrow  = lane >> 3;
    int lcol0 = (lane & 7) * 16;
    int gh    = gh0 + lrow;
    float cnth = (gh==0 || gh==H_-1) ? 2.f : 3.f;
    float w0  = (lcol0==0)        ? 2.f : 3.f;
    float w15 = (lcol0+15==W_-1)  ? 2.f : 3.f;

    const float* base0 = events + (size_t)(t0*B_+b)*CHW_ + c*HW_ + gh*W_ + lcol0;
    const size_t tstep = (size_t)B_ * CHW_;

    float px[16];
    if (t0 > 0){
        const float* pp = base0 - tstep;
        #pragma unroll
        for (int e=0;e<16;e+=4){
            float4 v = *reinterpret_cast<const float4*>(pp + e);
            px[e]=v.x; px[e+1]=v.y; px[e+2]=v.z; px[e+3]=v.w;
        }
    } else {
        #pragma unroll
        for (int e=0;e<16;e++) px[e]=0.f;
    }

    #pragma unroll 1
    for (int tt=0; tt<TC; ++tt){
        int t = t0 + tt;
        const float* src = base0 + (size_t)tt*tstep;

        float cx[16];
        #pragma unroll
        for (int e=0;e<16;e+=4){
            float4 v = *reinterpret_cast<const float4*>(src + e);
            cx[e]=v.x; cx[e+1]=v.y; cx[e+2]=v.z; cx[e+3]=v.w;
        }

        float ssum=0.f, smax=-INFINITY, q=0.f, dsu=0.f;
        #pragma unroll
        for (int e=0;e<16;e++){
            float x = cx[e];
            ssum += x;
            smax = fmaxf(smax, x);
            float w = (e==0) ? w0 : ((e==15) ? w15 : 3.f);
            q = fmaf(w*x, x, q);
            dsu += fabsf(x - px[e]);
            px[e] = x;
        }

        #pragma unroll
        for (int e=0;e<16;e+=4){
            float4 v; v.x=cx[e]; v.y=cx[e+1]; v.z=cx[e+2]; v.w=cx[e+3];
            *reinterpret_cast<float4*>(&xs[c][lane*16 + e]) = v;
        }
        __syncthreads();

        {
            int p0 = tid * 2;
            float y0=0.f, y1=0.f;
            #pragma unroll
            for (int cc=0; cc<C_; cc++){
                y0 += xs[cc][p0];
                y1 += xs[cc][p0+1];
            }
            float2 yy; yy.x=y0; yy.y=y1;
            *reinterpret_cast<float2*>(yfield + (size_t)(t*B_+b)*HW_ + gh0*W_ + p0) = yy;
        }

        float rs = wave_sum(ssum);
        float rm = wave_max(smax);
        float rd = wave_sum(dsu);
        float rq = wave_sum(cnth * q);
        if (lane == 0){
            float4 o; o.x=rs; o.y=rm; o.z=rd; o.w=rq;
            *reinterpret_cast<float4*>(
                partials + (((size_t)(t*B_+b)*NSL + s)*C_ + c)*4) = o;
        }
        __syncthreads();
    }
}

// ---------------- K1b: m1 from y-field ----------------
__global__ __launch_bounds__(256) void m1_kernel(
    const float* __restrict__ yfield, float* __restrict__ m1p)
{
    int bid = blockIdx.x;
    int s   = bid & 7;
    int tb  = bid >> 3;
    int h0  = s*16;
    int tid = threadIdx.x;
    __shared__ float yb[18][W_];

    const float* yf = yfield + (size_t)tb*HW_;
    for (int i = tid; i < 18*32; i += 256){
        int rr = i >> 5, cc = (i & 31) * 4;
        int gh = h0 - 1 + rr;
        float4 v; v.x=0.f; v.y=0.f; v.z=0.f; v.w=0.f;
        if (gh >= 0 && gh < H_) v = *reinterpret_cast<const float4*>(yf + gh*W_ + cc);
        *reinterpret_cast<float4*>(&yb[rr][cc]) = v;
    }
    __syncthreads();

    float m1 = 0.f;
    {
        int w  = tid & 127;
        int rg = tid >> 7;
        bool hasL = (w>0), hasR = (w<W_-1);
        int base = rg*8;
        const float* row;
        row = yb[base];   float a0 = row[w] + (hasL?row[w-1]:0.f) + (hasR?row[w+1]:0.f);
        row = yb[base+1]; float a1 = row[w] + (hasL?row[w-1]:0.f) + (hasR?row[w+1]:0.f);
        #pragma unroll
        for (int i=0;i<8;i++){
            row = yb[base+2+i];
            float a2 = row[w] + (hasL?row[w-1]:0.f) + (hasR?row[w+1]:0.f);
            float s1 = a0 + a1 + a2;
            m1 = fmaf(s1, s1, m1);
            a0 = a1; a1 = a2;
        }
    }
    m1 = wave_sum(m1);
    __shared__ float red2[4];
    int lane = tid & 63, wv = tid >> 6;
    if (lane==0) red2[wv] = m1;
    __syncthreads();
    if (tid==0) m1p[bid] = (red2[0]+red2[1])+(red2[2]+red2[3]);
}

// ---------------- K2: combine ----------------
__global__ __launch_bounds__(64) void combine_kernel(
    const float* __restrict__ partials,
    const float* __restrict__ m1p,
    const float* __restrict__ att_w1,
    const float* __restrict__ att_w2,
    const float* __restrict__ dwp, const float* __restrict__ twp,
    const float* __restrict__ mwp,
    float* __restrict__ beta_out, float* __restrict__ thr_out)
{
    int tb = blockIdx.x;
    int t  = tb / B_;
    int i  = threadIdx.x;
    __shared__ float v[19];
    const float* p = partials + (size_t)tb*NSL*C_*4;
    if (i < 8){
        float acc = 0.f;
        #pragma unroll
        for (int s=0;s<NSL;s++) acc += p[(s*C_ + i)*4 + 0];
        v[i] = acc;
    } else if (i < 16){
        int c = i - 8;
        float acc = -INFINITY;
        #pragma unroll
        for (int s=0;s<NSL;s++) acc = fmaxf(acc, p[(s*C_ + c)*4 + 1]);
        v[i] = acc;
    } else if (i == 16){
        float acc = 0.f;
        for (int k=0;k<NSL*C_;k++) acc += p[k*4 + 2];
        v[16] = acc;
    } else if (i == 17){
        const float* mp = m1p + (size_t)tb*8;
        float acc = 0.f;
        #pragma unroll
        for (int k=0;k<8;k++) acc += mp[k];
        v[17] = acc;
    } else if (i == 18){
        float acc = 0.f;
        for (int k=0;k<NSL*C_;k++) acc += p[k*4 + 3];
        v[18] = acc;
    }
    __syncthreads();
    if (i == 0){
        float h1 = 0.f;
        for (int c=0;c<C_;c++) h1 += v[8+c] * att_w1[c];
        for (int c=0;c<C_;c++) h1 += (v[c]/(float)HW_) * att_w1[C_+c];
        h1 = fmaxf(h1, 0.f);
        float total = 0.f;
        for (int c=0;c<C_;c++) total += v[c];
        float density  = total / (float)CHW_;
        float temporal = (t==0) ? 0.f : v[16] / (float)CHW_;
        float motion   = (v[18] - v[17]/72.f) / 71.f / (float)HW_;
        float z = dwp[0]*density + twp[0]*temporal + mwp[0]*motion;
        float adj = 2.f / (1.f + expf(-z));
        thr_out[tb] = 1.f + adj;
        for (int c=0;c<C_;c++){
            float sg = 1.f / (1.f + expf(-(h1 * att_w2[c])));
            beta_out[tb*C_ + c] = 0.5f + 0.45f*sg;
        }
    }
}

// ---------------- K3: LIF v3 — padded LDS, 4-px threads, 3-buffer, 1 barrier/t ----------------
__device__ __forceinline__ float fast_atan5(float x){
    // Hastings deg-5: atan(z) ~ z(a1 + z2(a3 + z2 a5)), |err| < 7e-4 rad on [0,1]
    float ax = fabsf(x);
    bool inv = ax > 1.f;
    float z  = inv ? __builtin_amdgcn_rcpf(ax) : ax;
    float z2 = z*z;
    float p = 0.0793331f;
    p = fmaf(p, z2, -0.2886790f);
    p = fmaf(p, z2,  0.9953540f);
    p = p * z;
    float r = inv ? (1.57079632679f - p) : p;
    return copysignf(r, x);
}

#define LST 136   // LDS row stride (floats); data cols 4..131, zero pads at 3 & 132
#define SR_ 10    // staged rows per buffer

__global__ __launch_bounds__(256, 4) void lif_kernel(
    const float* __restrict__ events,
    const float* __restrict__ conv_w,
    const float* __restrict__ beta,
    const float* __restrict__ thr,
    float* __restrict__ out)
{
    int bid  = blockIdx.x;
    int hblk = bid & 15;                // 16 bands of 8 rows
    int bc   = bid >> 4;
    int b = bc >> 3, c = bc & 7;
    int h0 = hblk * 8;
    int tid = threadIdx.x;

    float wk[9];
    #pragma unroll
    for (int k=0;k<9;k++) wk[k] = conv_w[c*9 + k];

    __shared__ float lds[3][SR_*LST];   // 3 x 5.44 KB

    // zero the pad columns once (stay zero: staging only writes data cols)
    if (tid < 60){
        int bsel = tid / 20, j = tid % 20;
        int row = j >> 1, col = (j & 1) ? 132 : 3;
        lds[bsel][row*LST + col] = 0.f;
    }

    // staging slots (float4): slot i in [0,320): row=i>>5, cg=i&31
    int rowA = tid >> 5,        cgA = tid & 31;
    int rowB = (256+tid) >> 5,  cgB = tid & 31;
    int ghA = h0 - 1 + rowA;
    int ghB = h0 - 1 + rowB;
    bool okA = (ghA >= 0) && (ghA < H_);
    bool okB = (tid < 64) && (ghB >= 0) && (ghB < H_);
    const float* baseFrame = events + ((size_t)(b*C_) + c) * HW_;
    const float* srcA = baseFrame + ghA*W_ + cgA*4;
    const float* srcB = baseFrame + ghB*W_ + cgB*4;
    const size_t tstep = (size_t)B_ * CHW_;
    int ldsA = rowA*LST + 4 + cgA*4;
    int ldsB = rowB*LST + 4 + cgB*4;

    // compute mapping: thread = (row r, 4-col group)
    int cg = tid & 31;
    int r  = tid >> 5;                  // output row r (global gh0+r), staged center = r+1
    int cbase = 4 + cg*4;               // LDS col of first owned px

    float v[4];
    #pragma unroll
    for (int i=0;i<4;i++) v[i] = 0.f;

    float4 z4; z4.x=0.f; z4.y=0.f; z4.z=0.f; z4.w=0.f;

    // prologue: stage t=0 into buf0; preload t=1 into regs
    {
        float4 sa = okA ? *reinterpret_cast<const float4*>(srcA) : z4;
        float4 sb = okB ? *reinterpret_cast<const float4*>(srcB) : z4;
        *reinterpret_cast<float4*>(&lds[0][ldsA]) = sa;
        if (tid < 64) *reinterpret_cast<float4*>(&lds[0][ldsB]) = sb;
    }
    float4 rA = okA ? *reinterpret_cast<const float4*>(srcA + tstep) : z4;
    float4 rB = okB ? *reinterpret_cast<const float4*>(srcB + tstep) : z4;
    __syncthreads();

    const float* bp = beta + (b*C_ + c);
    const float* tp = thr + b;
    float bv = bp[0];
    float th = tp[0];

    int cur = 0;
    #pragma unroll 1
    for (int t = 0; t < T_; ++t){
        int nxt = cur + 1; if (nxt == 3) nxt = 0;

        // write staged regs (t+1) into buf[nxt]
        if (t + 1 < T_){
            *reinterpret_cast<float4*>(&lds[nxt][ldsA]) = rA;
            if (tid < 64) *reinterpret_cast<float4*>(&lds[nxt][ldsB]) = rB;
        }
        // issue loads for t+2
        if (t + 2 < T_){
            rA = okA ? *reinterpret_cast<const float4*>(srcA + (size_t)(t+2)*tstep) : z4;
            rB = okB ? *reinterpret_cast<const float4*>(srcB + (size_t)(t+2)*tstep) : z4;
        }
        float bvn = (t+1 < T_) ? bp[(size_t)(t+1)*B_*C_] : 0.f;
        float thn = (t+1 < T_) ? tp[(size_t)(t+1)*B_]    : 0.f;

        // compute t from buf[cur]
        const float* Lr = &lds[cur][r*LST + cbase];   // staged row r = gh0+r-1
        float4 um = *reinterpret_cast<const float4*>(Lr);
        float  lm = Lr[-1],        rm = Lr[4];
        const float* Lc = Lr + LST;
        float4 uc = *reinterpret_cast<const float4*>(Lc);
        float  lc = Lc[-1],        rc = Lc[4];
        const float* Lp = Lc + LST;
        float4 up = *reinterpret_cast<const float4*>(Lp);
        float  lp = Lp[-1],        rp = Lp[4];

        float omb = 1.f - bv;
        float th2 = 2.f * th;

        float wi0 = wk[0]*lm   + wk[1]*um.x + wk[2]*um.y
                  + wk[3]*lc   + wk[4]*uc.x + wk[5]*uc.y
                  + wk[6]*lp   + wk[7]*up.x + wk[8]*up.y;
        float wi1 = wk[0]*um.x + wk[1]*um.y + wk[2]*um.z
                  + wk[3]*uc.x + wk[4]*uc.y + wk[5]*uc.z
                  + wk[6]*up.x + wk[7]*up.y + wk[8]*up.z;
        float wi2 = wk[0]*um.y + wk[1]*um.z + wk[2]*um.w
                  + wk[3]*uc.y + wk[4]*uc.z + wk[5]*uc.w
                  + wk[6]*up.y + wk[7]*up.z + wk[8]*up.w;
        float wi3 = wk[0]*um.z + wk[1]*um.w + wk[2]*rm
                  + wk[3]*uc.z + wk[4]*uc.w + wk[5]*rc
                  + wk[6]*up.z + wk[7]*up.w + wk[8]*rp;

        float vv0 = fmaf(bv, v[0], omb*wi0);
        float vv1 = fmaf(bv, v[1], omb*wi1);
        float vv2 = fmaf(bv, v[2], omb*wi2);
        float vv3 = fmaf(bv, v[3], omb*wi3);

        float sp0 = fmaf(fast_atan5(fmaf(2.f, vv0, -th2)), 0.5f, 0.5f);
        float sp1 = fmaf(fast_atan5(fmaf(2.f, vv1, -th2)), 0.5f, 0.5f);
        float sp2 = fmaf(fast_atan5(fmaf(2.f, vv2, -th2)), 0.5f, 0.5f);
        float sp3 = fmaf(fast_atan5(fmaf(2.f, vv3, -th2)), 0.5f, 0.5f);

        f32x4 o;
        o.x = uc.x * sp0;  o.y = uc.y * sp1;
        o.z = uc.z * sp2;  o.w = uc.w * sp3;
        f32x4* op = reinterpret_cast<f32x4*>(
            out + ((size_t)(t*B_+b)*C_ + c)*HW_ + (h0+r)*W_ + cg*4);
        __builtin_nontemporal_store(o, op);

        v[0] = (1.f - sp0) * vv0;
        v[1] = (1.f - sp1) * vv1;
        v[2] = (1.f - sp2) * vv2;
        v[3] = (1.f - sp3) * vv3;

        __syncthreads();    // buf[nxt] staged + everyone done reading buf[cur]
        bv = bvn; th = thn;
        cur = nxt;
    }
}

extern "C" void kernel_launch(void* const* d_in, const int* in_sizes, int n_in,
                              void* d_out, int out_size, void* d_ws, size_t ws_size,
                              hipStream_t stream)
{
    const float* events = (const float*)d_in[0];
    const float* conv_w = (const float*)d_in[1];
    const float* att_w1 = (const float*)d_in[2];
    const float* att_w2 = (const float*)d_in[3];
    const float* dwp    = (const float*)d_in[4];
    const float* twp    = (const float*)d_in[5];
    const float* mwp    = (const float*)d_in[6];
    float* out = (float*)d_out;

    float* ws       = (float*)d_ws;
    float* partials = ws;
    float* m1p      = partials + (size_t)T_*B_*NSL*C_*4;
    float* beta     = m1p + (size_t)T_*B_*8;
    float* thr      = beta + (size_t)T_*B_*C_;
    float* yfield   = thr + T_*B_;

    stats_kernel  <<<B_*NSL*4,  512, 0, stream>>>(events, partials, yfield);
    m1_kernel     <<<T_*B_*8,   256, 0, stream>>>(yfield, m1p);
    combine_kernel<<<T_*B_,     64,  0, stream>>>(partials, m1p, att_w1, att_w2,
                                                  dwp, twp, mwp, beta, thr);
    lif_kernel    <<<B_*C_*16,  256, 0, stream>>>(events, conv_w, beta, thr, out);
}